// Round 12
// baseline (40676.093 us; speedup 1.0000x reference)
//
#include <hip/hip_runtime.h>
#include <math.h>

typedef unsigned int u32;

#define T_SEQ   2048
#define NWG     512

// ---------------- workspace layout (bytes) ----------------
#define OFF_HBUF   0            // float[2][32][512] = 131072
#define OFF_CNT    131072       // u32[4][8][32] (sub-counters 128B apart) = 4096
#define OFF_LASTH  135168       // float[32][512] = 65536
#define WS_NEED    200704ull

// ---------------- fallback (round-2 proven) layout ----------------
#define FB_OFF_HBUF   0
#define FB_OFF_ARRIVE 131072
#define FB_OFF_LASTH  131328

__device__ __forceinline__ float sigm(float x) { return 1.0f / (1.0f + expf(-x)); }

// ---- LLC-coherent accessors (sc0 sc1 = bypass L1 + XCD L2); r8/r10-proven ----
__device__ __forceinline__ float4 ldg4s(const float* p) {
  float4 v;
  asm volatile("global_load_dwordx4 %0, %1, off sc0 sc1" : "=v"(v) : "v"(p) : "memory");
  return v;
}
__device__ __forceinline__ void stg1fs(float* p, float v) {
  asm volatile("global_store_dword %0, %1, off sc0 sc1" :: "v"(p), "v"(v) : "memory");
}

// =====================================================================
// Sequential LSTM v7: 512 WGs x 256 threads, 2 WGs/CU (LDS ~17.5 KB).
// r11 diagnosis: 1 WG/CU = 1 wave/SIMD -> all LDS/global latency exposed
// (VALUBusy 25%). v7: ug = bid>>2 owns 4 units (16 gate rows, wave wv =
// gate wv, units ug*4..+4); bg = bid&3 owns 8 batches.
// W fragment = 4 rows x 16 floats x 2 phases = 32 VGPRs, PERMANENTLY in
// registers (no W LDS reads at all; r10 spent 64 ds_read_b128/thread/step
// reloading W). Per-thread FMA halves to 512/step.
// Lane map: bit0 -> batch half (bb0), bit1 -> kk, bits2-5 -> kg;
// k-slice = 16 floats at kg*32+kk*16 within each 512-wide phase.
// k-reduction: 5x shfl_xor (masks 2,4,8,16,32) - fully intra-wave.
// h: sc0sc1 -> swizzled Hl (r10 formula; reads 2 lanes/bank = free).
// Sync: 8 sub-counters/bg (128B apart), target 16t; h drained vmcnt(0)
// before post; watchdog -> sticky dead -> free-run (no hang).
// =====================================================================
__global__ void __launch_bounds__(256, 2)
lstm_seq(const int* __restrict__ x, const int* __restrict__ attn,
         const float* __restrict__ emb,
         const float* __restrict__ Wih, const float* __restrict__ Whh,
         const float* __restrict__ bih, const float* __restrict__ bhh,
         float* __restrict__ hbuf, u32* __restrict__ counters,
         float* __restrict__ lasth)
{
  __shared__ __align__(16) float4 Hl4[1024];   // [8 b][128 chunks] swizzled
  __shared__ float gsc[256];                   // gates [16 rows][8 b] / len scratch
  __shared__ int s_dead;

  const int tid = threadIdx.x, bid = blockIdx.x;
  const int ug = bid >> 2, bg = bid & 3;
  const int wv = tid >> 6, lane = tid & 63;
  const int kg  = (lane >> 2) & 15;            // lane bits 2..5
  const int kk  = (lane >> 1) & 1;             // lane bit 1
  const int bb0 = (lane & 1) * 4;              // lane bit 0 -> batches bb0..+4
  const int ksf = kg * 32 + kk * 16;           // k-slice base (floats) in [0,512)
  const int cb  = kg * 8 + kk * 4;             // chunk base for Hl reads

  u32* cntb  = counters + bg * 256;            // 8 sub-counters, 128B apart
  u32* mycnt = cntb + (ug & 7) * 32;

  // ---- W fragments -> registers (once): 4 rows x 4 float4 x 2 phases ----
  float4 wE[4][4], wH[4][4];
#pragma unroll
  for (int i = 0; i < 4; ++i) {
    int R = wv * 512 + ug * 4 + i;             // gate wv, unit ug*4+i
    const float4* pE = (const float4*)(Wih + (size_t)R * 512 + ksf);
    const float4* pH = (const float4*)(Whh + (size_t)R * 512 + ksf);
#pragma unroll
    for (int q = 0; q < 4; ++q) { wE[i][q] = pE[q]; wH[i][q] = pH[q]; }
  }

  // ---- lengths (partials in gsc as [32 chunks][8 b]) ----
  {
    int b = tid & 7, c = tid >> 3;             // c in [0,32)
    const int4* ap = (const int4*)(attn + (size_t)(bg * 8 + b) * 2048 + c * 64);
    int s = 0;
#pragma unroll
    for (int k = 0; k < 16; ++k) { int4 a = ap[k]; s += a.x + a.y + a.z + a.w; }
    gsc[c * 8 + b] = (float)s;
  }
  if (tid == 0) s_dead = 0;
  __syncthreads();
  int len = 0; float c_reg = 0.f;
  float bI = 0, bF = 0, bG = 0, bO = 0;
  if (tid < 32) {
    int b = tid & 7, uu = tid >> 3;            // unit 0..3
    int s = 0;
#pragma unroll
    for (int c = 0; c < 32; ++c) s += (int)gsc[c * 8 + b];
    len = s - 1; if (len < 0) len = T_SEQ - 1;
    int gu = ug * 4 + uu;
    bI = bih[gu]        + bhh[gu];
    bF = bih[512 + gu]  + bhh[512 + gu];
    bG = bih[1024 + gu] + bhh[1024 + gu];
    bO = bih[1536 + gu] + bhh[1536 + gu];
  }
  __syncthreads();   // gsc reusable

  bool dead = false;

  for (int t = 0; t < T_SEQ; ++t) {
    float acc[4][4];
#pragma unroll
    for (int i = 0; i < 4; ++i) { acc[i][0] = 0.f; acc[i][1] = 0.f; acc[i][2] = 0.f; acc[i][3] = 0.f; }

    // ---- emb phase (h-independent; overlaps producer tail) ----
#pragma unroll
    for (int jb = 0; jb < 4; ++jb) {
      int xr = x[(size_t)(bg * 8 + bb0 + jb) * 2048 + t];
      const float4* ep = (const float4*)(emb + (size_t)xr * 512 + ksf);
      float4 e[4];
#pragma unroll
      for (int q = 0; q < 4; ++q) e[q] = ep[q];
#pragma unroll
      for (int q = 0; q < 4; ++q)
#pragma unroll
        for (int i = 0; i < 4; ++i) {
          acc[i][jb] += wE[i][q].x * e[q].x; acc[i][jb] += wE[i][q].y * e[q].y;
          acc[i][jb] += wE[i][q].z * e[q].z; acc[i][jb] += wE[i][q].w * e[q].w;
        }
    }

    // ---- barrier: lanes 0..7 of wave0 poll the 8 sub-counters ----
    if (tid < 8 && !dead) {
      const u32 target = (u32)(t << 4);        // 16 posts per sub-counter per step
      const u32* myc = cntb + tid * 32;
      int it = 0;
      while (true) {
        u32 v = __hip_atomic_load(myc, __ATOMIC_RELAXED, __HIP_MEMORY_SCOPE_AGENT);
        if (__all((int)v >= (int)target)) break;
        if (++it > (1 << 17)) { s_dead = 1; break; }   // watchdog: no hang
        __builtin_amdgcn_s_sleep(1);
      }
    }
    __syncthreads();
    if (s_dead) dead = true;

    // ---- h stage: 4 unique coalesced sc0sc1 float4/thread -> swizzled Hl ----
    {
      const float* hsrc = hbuf + (((t + 1) & 1) << 14) + (size_t)(bg * 8) * 512;
      float4 hv[4];
      int pp[4];
#pragma unroll
      for (int k = 0; k < 4; ++k) {
        int cf = tid + k * 256;                // 0..1023
        int b = cf >> 7, c = cf & 127;
        hv[k] = ldg4s(hsrc + (size_t)b * 512 + c * 4);
        pp[k] = b * 128 + (c & ~7) + (((c & 7) + (c >> 3) + b) & 7);
      }
      asm volatile("s_waitcnt vmcnt(0)" ::: "memory");
      __builtin_amdgcn_sched_barrier(0);
#pragma unroll
      for (int k = 0; k < 4; ++k) Hl4[pp[k]] = hv[k];
    }
    __syncthreads();

    // ---- h phase: W from regs, u from swizzled Hl ----
#pragma unroll
    for (int jb = 0; jb < 4; ++jb) {
      int bl = bb0 + jb;
      float4 e[4];
#pragma unroll
      for (int q = 0; q < 4; ++q) {
        int c = cb + q;
        e[q] = Hl4[bl * 128 + (c & ~7) + (((c & 7) + (c >> 3) + bl) & 7)];
      }
#pragma unroll
      for (int q = 0; q < 4; ++q)
#pragma unroll
        for (int i = 0; i < 4; ++i) {
          acc[i][jb] += wH[i][q].x * e[q].x; acc[i][jb] += wH[i][q].y * e[q].y;
          acc[i][jb] += wH[i][q].z * e[q].z; acc[i][jb] += wH[i][q].w * e[q].w;
        }
    }

    // ---- k-reduction: 5x shfl_xor over lane bits 1..5 (kk + kg) ----
#pragma unroll
    for (int i = 0; i < 4; ++i)
#pragma unroll
      for (int j = 0; j < 4; ++j) {
        float v = acc[i][j];
        v += __shfl_xor(v, 2, 64);
        v += __shfl_xor(v, 4, 64);
        v += __shfl_xor(v, 8, 64);
        v += __shfl_xor(v, 16, 64);
        v += __shfl_xor(v, 32, 64);
        acc[i][j] = v;
      }
    if (lane < 2) {                            // lane0: batches 0..3, lane1: 4..7
#pragma unroll
      for (int i = 0; i < 4; ++i)
#pragma unroll
        for (int j = 0; j < 4; ++j)
          gsc[(wv * 4 + i) * 8 + lane * 4 + j] = acc[i][j];
    }
    __syncthreads();

    // ---- activations + sc0sc1 h post (wave 0), then sub-counter post ----
    if (tid < 64) {
      if (tid < 32) {
        int b = tid & 7, uu = tid >> 3;
        float gi = gsc[(0  + uu) * 8 + b] + bI;
        float gf = gsc[(4  + uu) * 8 + b] + bF;
        float gg = gsc[(8  + uu) * 8 + b] + bG;
        float go = gsc[(12 + uu) * 8 + b] + bO;
        float iv = sigm(gi), fv = sigm(gf), ov = sigm(go), gv = tanhf(gg);
        c_reg = fv * c_reg + iv * gv;
        float hval = ov * tanhf(c_reg);
        int bglob = bg * 8 + b, unit = ug * 4 + uu;
        float* hd = hbuf + ((t & 1) << 14) + (bglob << 9) + unit;
        stg1fs(hd, hval);
        if (t == len) lasth[(bglob << 9) + unit] = hval;
      }
      asm volatile("s_waitcnt vmcnt(0)" ::: "memory");   // wave0 stores at LLC
      if (tid == 0)
        __hip_atomic_fetch_add(mycnt, 1u, __ATOMIC_RELAXED, __HIP_MEMORY_SCOPE_AGENT);
    }
  }
}

// =====================================================================
// FC head
// =====================================================================
__global__ void __launch_bounds__(128)
fc_kernel(const float* __restrict__ lasth, const float* __restrict__ fcW,
          const float* __restrict__ fcb, float* __restrict__ out)
{
  int tid = threadIdx.x;
  int b = tid >> 2, n = tid & 3;
  const float4* h4 = (const float4*)(lasth + (size_t)b * 512);
  const float4* w4 = (const float4*)(fcW + (size_t)n * 512);
  float s0 = 0.f, s1 = 0.f, s2 = 0.f, s3 = 0.f;
#pragma unroll 8
  for (int k = 0; k < 128; ++k) {
    float4 a = h4[k], c = w4[k];
    s0 += a.x * c.x; s1 += a.y * c.y; s2 += a.z * c.z; s3 += a.w * c.w;
  }
  out[b * 4 + n] = fcb[n] + ((s0 + s1) + (s2 + s3));
}

// =====================================================================
// Fallback: round-2 proven persistent kernel (only if ws too small)
// =====================================================================
__device__ __forceinline__ void gl2lds16(const void* gsrc, void* ldst) {
  __builtin_amdgcn_global_load_lds(
      (const __attribute__((address_space(1))) u32*)gsrc,
      (__attribute__((address_space(3))) u32*)ldst, 16, 0, 0);
}

__global__ void __launch_bounds__(256)
lstm_persist(const int* __restrict__ xidx, const int* __restrict__ attn,
             const float* __restrict__ emb,
             const float* __restrict__ Wih, const float* __restrict__ Whh,
             const float* __restrict__ bih, const float* __restrict__ bhh,
             float* __restrict__ hbuf, float* __restrict__ lasth,
             u32* __restrict__ arrive)
{
  __shared__ __align__(16) float Wl[8][1024];
  __shared__ __align__(16) float ul[2][32][64];
  __shared__ float gsc[32][8];

  const int tid  = threadIdx.x;
  const int wg   = blockIdx.x;
  const int lane = tid & 63;
  const int wv   = tid >> 6;
  const int r    = tid & 7;
  const int bb   = tid >> 3;
  const int brl  = bb & 7;

#pragma unroll 2
  for (int i = 0; i < 8; ++i) {
    int ci = i * 256 + tid;
    int rr = ci >> 8;
    int cc = ci & 255;
    int R  = ((rr >> 1) << 9) + (wg * 2 + (rr & 1));
    const float* src = (cc < 128) ? (Wih + (size_t)R * 512 + cc * 4)
                                  : (Whh + (size_t)R * 512 + (cc - 128) * 4);
    float4 v = *(const float4*)src;
    int slot = cc ^ (rr & 7);
    *(float4*)&Wl[rr][slot * 4] = v;
  }
  float bias;
  {
    int R = ((r >> 1) << 9) + (wg * 2 + (r & 1));
    bias = bih[R] + bhh[R];
  }
  {
    int pb = tid >> 3, pc = tid & 7;
    const int4* ap = (const int4*)(attn + pb * 2048 + pc * 256);
    int s = 0;
#pragma unroll 8
    for (int k = 0; k < 64; ++k) { int4 a = ap[k]; s += a.x + a.y + a.z + a.w; }
    gsc[pb][pc] = (float)s;
  }
  __syncthreads();
  int   len_reg = 0;
  float c_reg   = 0.f;
  if (tid < 64) {
    int b2 = tid & 31;
    int s = 0;
#pragma unroll
    for (int k = 0; k < 8; ++k) s += (int)gsc[b2][k];
    len_reg = s - 1;
    if (len_reg < 0) len_reg = 2047;
  }
  __syncthreads();

  const int idx_b = 8 * wv + (lane & 7);
  int idx_cur = xidx[(size_t)idx_b * 2048];

  for (int t = 0; t < T_SEQ; ++t) {
    int idx_next = (t < T_SEQ - 1) ? xidx[(size_t)idx_b * 2048 + t + 1] : 0;
    float a0 = bias, a1 = 0.f, a2 = 0.f, a3 = 0.f;
    const float* hsrc = hbuf + (((t + 1) & 1) << 14);

    auto stageE = [&](int jt, int buf) {
#pragma unroll
      for (int q = 0; q < 2; ++q) {
        int rlq = 4 * q + (lane >> 4);
        int sc = lane & 15;
        int kc = sc ^ (rlq & 7);
        int rowg = __shfl(idx_cur, rlq, 64);
        const float* g = emb + (size_t)rowg * 512 + jt * 64 + kc * 4;
        gl2lds16(g, (void*)&ul[buf][8 * wv + 4 * q][0]);
      }
    };
    auto stageH = [&](int jt, int buf) {
#pragma unroll
      for (int q = 0; q < 2; ++q) {
        int rlq = 4 * q + (lane >> 4);
        int sc = lane & 15;
        int kc = sc ^ (rlq & 7);
        int blq = 8 * wv + rlq;
        const float* g = hsrc + (size_t)blq * 512 + jt * 64 + kc * 4;
        gl2lds16(g, (void*)&ul[buf][8 * wv + 4 * q][0]);
      }
    };
    auto computeT = [&](int jg, int buf) {
#pragma unroll
      for (int kc = 0; kc < 16; ++kc) {
        float4 uv4 = *(const float4*)&ul[buf][bb][(kc ^ brl) * 4];
        float4 wv4 = *(const float4*)&Wl[r][(((jg << 4) + kc) ^ r) * 4];
        a0 += uv4.x * wv4.x; a1 += uv4.y * wv4.y;
        a2 += uv4.z * wv4.z; a3 += uv4.w * wv4.w;
      }
    };

    stageE(0, 0);
#pragma unroll
    for (int jt = 0; jt < 8; ++jt) {
      if (jt < 7) { stageE(jt + 1, (jt + 1) & 1); asm volatile("s_waitcnt vmcnt(2)" ::: "memory"); }
      else       { asm volatile("s_waitcnt vmcnt(0)" ::: "memory"); }
      computeT(jt, jt & 1);
    }

    if (tid == 0) {
      u32 target = (u32)t << 8;
      while (__hip_atomic_load(arrive, __ATOMIC_RELAXED, __HIP_MEMORY_SCOPE_AGENT) < target)
        __builtin_amdgcn_s_sleep(2);
    }
    __syncthreads();
    __builtin_amdgcn_fence(__ATOMIC_ACQUIRE, "agent");

    stageH(0, 0);
#pragma unroll
    for (int jt = 0; jt < 8; ++jt) {
      if (jt < 7) { stageH(jt + 1, (jt + 1) & 1); asm volatile("s_waitcnt vmcnt(2)" ::: "memory"); }
      else       { asm volatile("s_waitcnt vmcnt(0)" ::: "memory"); }
      computeT(8 + jt, jt & 1);
    }

    gsc[bb][r] = a0 + a1 + a2 + a3;
    __syncthreads();
    if (tid < 64) {
      int u  = tid >> 5;
      int b2 = tid & 31;
      float gi = gsc[b2][u];
      float gf = gsc[b2][2 + u];
      float gg = gsc[b2][4 + u];
      float go = gsc[b2][6 + u];
      float iv = sigm(gi), fv = sigm(gf), ov = sigm(go);
      float gv = tanhf(gg);
      c_reg = fv * c_reg + iv * gv;
      float hv = ov * tanhf(c_reg);
      int unit = (wg << 1) + u;
      hbuf[((t & 1) << 14) + (b2 << 9) + unit] = hv;
      if (t == len_reg) lasth[(b2 << 9) + unit] = hv;
      __builtin_amdgcn_fence(__ATOMIC_RELEASE, "agent");
      if (tid == 0)
        __hip_atomic_fetch_add(arrive, 1u, __ATOMIC_RELAXED, __HIP_MEMORY_SCOPE_AGENT);
    }
    idx_cur = idx_next;
  }
}

extern "C" void kernel_launch(void* const* d_in, const int* in_sizes, int n_in,
                              void* d_out, int out_size, void* d_ws, size_t ws_size,
                              hipStream_t stream) {
  const int*   x    = (const int*)d_in[0];
  const int*   attn = (const int*)d_in[1];
  const float* emb  = (const float*)d_in[2];
  const float* Wih  = (const float*)d_in[3];
  const float* Whh  = (const float*)d_in[4];
  const float* bih  = (const float*)d_in[5];
  const float* bhh  = (const float*)d_in[6];
  const float* fcW  = (const float*)d_in[7];
  const float* fcb  = (const float*)d_in[8];
  float* out = (float*)d_out;
  char* ws = (char*)d_ws;

  if (ws_size >= WS_NEED) {
    float* hbuf  = (float*)(ws + OFF_HBUF);
    u32*   cnts  = (u32*)(ws + OFF_CNT);
    float* lasth = (float*)(ws + OFF_LASTH);

    (void)hipMemsetAsync(ws, 0, OFF_LASTH, stream);   // hbuf + counters

    hipLaunchKernelGGL(lstm_seq, dim3(NWG), dim3(256), 0, stream,
                       x, attn, emb, Wih, Whh, bih, bhh, hbuf, cnts, lasth);
    hipLaunchKernelGGL(fc_kernel, dim3(1), dim3(128), 0, stream,
                       lasth, fcW, fcb, out);
  } else {
    float* hbuf   = (float*)(ws + FB_OFF_HBUF);
    u32*   arrive = (u32*)(ws + FB_OFF_ARRIVE);
    float* lasth  = (float*)(ws + FB_OFF_LASTH);
    (void)hipMemsetAsync(ws, 0, 131072 + 256, stream);
    hipLaunchKernelGGL(lstm_persist, dim3(256), dim3(256), 0, stream,
                       x, attn, emb, Wih, Whh, bih, bhh, hbuf, lasth, arrive);
    hipLaunchKernelGGL(fc_kernel, dim3(1), dim3(128), 0, stream,
                       lasth, fcW, fcb, out);
  }
}

// Round 13
// 23530.696 us; speedup vs baseline: 1.7286x; 1.7286x over previous
//
#include <hip/hip_runtime.h>
#include <math.h>

typedef unsigned int u32;

#define T_SEQ   2048
#define NWG     512

// ---------------- workspace layout (bytes) ----------------
#define OFF_HBUF   0            // float[2][32][512] = 131072
#define OFF_CNT    131072       // u32[4][8][32] (sub-counters 128B apart) = 4096
#define OFF_LASTH  135168       // float[32][512] = 65536
#define WS_NEED    200704ull

// ---------------- fallback (round-2 proven) layout ----------------
#define FB_OFF_HBUF   0
#define FB_OFF_ARRIVE 131072
#define FB_OFF_LASTH  131328

__device__ __forceinline__ float sigm(float x) { return 1.0f / (1.0f + expf(-x)); }

// ---- LLC-coherent accessors (sc0 sc1 = bypass L1 + XCD L2); r8/r10-proven ----
__device__ __forceinline__ float4 ldg4s(const float* p) {
  float4 v;
  asm volatile("global_load_dwordx4 %0, %1, off sc0 sc1" : "=v"(v) : "v"(p) : "memory");
  return v;
}
__device__ __forceinline__ void stg1fs(float* p, float v) {
  asm volatile("global_store_dword %0, %1, off sc0 sc1" :: "v"(p), "v"(v) : "memory");
}

// =====================================================================
// Sequential LSTM v8: 512 WGs x 256 threads, 2 WGs/CU (VGPR cap 128).
// r12 lesson: W-in-regs must fit the 128-reg budget WITHOUT duplication.
// ug = bid>>2 owns 4 units (16 gate rows); bg = bid&3 owns 8 batches.
// Wave wv = gate; LANE = K: thread k-slice = {lane + 64j, j<8} per phase
// (scalar elements). Thread owns 4 unit-rows x ALL 8 batches.
//   W/thread = 16rows*1024 / 256thr = 64 f32 VGPRs (exact minimum).
//   acc[4][8] = 32.  Peak ~124 regs < 128 -> no spill (r6-r12's killer).
// Operand geometry (scalar, lane-stride 4B):
//   emb: global scalar loads, 64 lanes consecutive = coalesced.
//   h:   Hl[8][512] natural layout; ds_read_b32 lane-consecutive =
//        conflict-free; staging = 4 coalesced sc0sc1 float4/thread with
//        lane-contiguous LDS writes (canonical). NO swizzle anywhere.
// Reduction: 6x shfl_xor over all 64 lanes (k), statically-predicated
// gsc writes (no runtime reg indexing -> no scratch).
// Sync: r12-proven 8 sub-counters/bg (128B apart), target 16t; h posted
// sc0sc1 + vmcnt(0) before post; watchdog -> sticky dead (no hang).
// =====================================================================
__global__ void __launch_bounds__(256, 2)
lstm_seq(const int* __restrict__ x, const int* __restrict__ attn,
         const float* __restrict__ emb,
         const float* __restrict__ Wih, const float* __restrict__ Whh,
         const float* __restrict__ bih, const float* __restrict__ bhh,
         float* __restrict__ hbuf, u32* __restrict__ counters,
         float* __restrict__ lasth)
{
  __shared__ __align__(16) float Hl[8 * 512];  // natural [b][k] layout
  __shared__ float gsc[256];                   // [gate][unit][b] = 128 used
  __shared__ int s_dead;

  const int tid = threadIdx.x, bid = blockIdx.x;
  const int ug = bid >> 2, bg = bid & 3;
  const int wv = tid >> 6, lane = tid & 63;

  u32* cntb  = counters + bg * 256;            // 8 sub-counters, 128B apart
  u32* mycnt = cntb + (ug & 7) * 32;

  // ---- W fragments -> registers (once): 4 rows x 8 scalars x 2 phases ----
  float wE[4][8], wH[4][8];
#pragma unroll
  for (int i = 0; i < 4; ++i) {
    int R = wv * 512 + ug * 4 + i;             // gate wv, unit ug*4+i
    const float* pE = Wih + (size_t)R * 512 + lane;
    const float* pH = Whh + (size_t)R * 512 + lane;
#pragma unroll
    for (int j = 0; j < 8; ++j) { wE[i][j] = pE[64 * j]; wH[i][j] = pH[64 * j]; }
  }

  // ---- lengths (partials in gsc as [32 chunks][8 b]) ----
  {
    int b = tid & 7, c = tid >> 3;             // c in [0,32)
    const int4* ap = (const int4*)(attn + (size_t)(bg * 8 + b) * 2048 + c * 64);
    int s = 0;
#pragma unroll
    for (int k = 0; k < 16; ++k) { int4 a = ap[k]; s += a.x + a.y + a.z + a.w; }
    gsc[c * 8 + b] = (float)s;
  }
  if (tid == 0) s_dead = 0;
  __syncthreads();
  int len = 0; float c_reg = 0.f;
  float bI = 0, bF = 0, bG = 0, bO = 0;
  if (tid < 32) {
    int b = tid & 7, uu = tid >> 3;            // unit 0..3
    int s = 0;
#pragma unroll
    for (int c = 0; c < 32; ++c) s += (int)gsc[c * 8 + b];
    len = s - 1; if (len < 0) len = T_SEQ - 1;
    int gu = ug * 4 + uu;
    bI = bih[gu]        + bhh[gu];
    bF = bih[512 + gu]  + bhh[512 + gu];
    bG = bih[1024 + gu] + bhh[1024 + gu];
    bO = bih[1536 + gu] + bhh[1536 + gu];
  }
  __syncthreads();   // gsc reusable

  bool dead = false;

  for (int t = 0; t < T_SEQ; ++t) {
    float acc[4][8];
#pragma unroll
    for (int i = 0; i < 4; ++i)
#pragma unroll
      for (int b = 0; b < 8; ++b) acc[i][b] = 0.f;

    // ---- emb phase (h-independent; overlaps producer tail) ----
#pragma unroll 2
    for (int b = 0; b < 8; ++b) {
      int xr = x[(size_t)(bg * 8 + b) * 2048 + t];       // lane-uniform -> SGPR
      const float* ep = emb + (size_t)xr * 512 + lane;
#pragma unroll
      for (int j = 0; j < 8; ++j) {
        float e = ep[64 * j];
        acc[0][b] += wE[0][j] * e;
        acc[1][b] += wE[1][j] * e;
        acc[2][b] += wE[2][j] * e;
        acc[3][b] += wE[3][j] * e;
      }
    }

    // ---- barrier: lanes 0..7 of wave0 poll the 8 sub-counters ----
    if (tid < 8 && !dead) {
      const u32 target = (u32)(t << 4);        // 16 posts per sub-counter per step
      const u32* myc = cntb + tid * 32;
      int it = 0;
      while (true) {
        u32 v = __hip_atomic_load(myc, __ATOMIC_RELAXED, __HIP_MEMORY_SCOPE_AGENT);
        if (__all((int)v >= (int)target)) break;
        if (++it > (1 << 17)) { s_dead = 1; break; }   // watchdog: no hang
        __builtin_amdgcn_s_sleep(1);
      }
    }
    __syncthreads();
    if (s_dead) dead = true;

    // ---- h stage: 4 coalesced sc0sc1 float4/thread -> natural-layout Hl ----
    {
      const float* hsrc = hbuf + (((t + 1) & 1) << 14) + (size_t)(bg * 8) * 512;
      float4 hv0 = ldg4s(hsrc + (size_t)(tid +   0) * 4);
      float4 hv1 = ldg4s(hsrc + (size_t)(tid + 256) * 4);
      float4 hv2 = ldg4s(hsrc + (size_t)(tid + 512) * 4);
      float4 hv3 = ldg4s(hsrc + (size_t)(tid + 768) * 4);
      asm volatile("s_waitcnt vmcnt(0)" ::: "memory");
      __builtin_amdgcn_sched_barrier(0);
      *(float4*)&Hl[(tid +   0) * 4] = hv0;
      *(float4*)&Hl[(tid + 256) * 4] = hv1;
      *(float4*)&Hl[(tid + 512) * 4] = hv2;
      *(float4*)&Hl[(tid + 768) * 4] = hv3;
    }
    __syncthreads();

    // ---- h phase: W from regs, operands scalar from Hl (conflict-free) ----
#pragma unroll 2
    for (int b = 0; b < 8; ++b) {
      const float* hp = Hl + b * 512 + lane;
#pragma unroll
      for (int j = 0; j < 8; ++j) {
        float e = hp[64 * j];
        acc[0][b] += wH[0][j] * e;
        acc[1][b] += wH[1][j] * e;
        acc[2][b] += wH[2][j] * e;
        acc[3][b] += wH[3][j] * e;
      }
    }

    // ---- k-reduction: full 64-lane xor tree (all lanes end with sums) ----
#pragma unroll
    for (int i = 0; i < 4; ++i)
#pragma unroll
      for (int b = 0; b < 8; ++b) {
        float v = acc[i][b];
        v += __shfl_xor(v, 1, 64);
        v += __shfl_xor(v, 2, 64);
        v += __shfl_xor(v, 4, 64);
        v += __shfl_xor(v, 8, 64);
        v += __shfl_xor(v, 16, 64);
        v += __shfl_xor(v, 32, 64);
        acc[i][b] = v;
      }
    // statically-predicated writes: lane i*8+b publishes acc[i][b]
#pragma unroll
    for (int i = 0; i < 4; ++i)
#pragma unroll
      for (int b = 0; b < 8; ++b)
        if (lane == i * 8 + b)
          gsc[wv * 32 + i * 8 + b] = acc[i][b];
    __syncthreads();

    // ---- activations + sc0sc1 h post (wave0 lanes 0..31), counter post ----
    if (tid < 32) {
      int b = tid & 7, uu = tid >> 3;
      float gi = gsc[ 0 + uu * 8 + b] + bI;
      float gf = gsc[32 + uu * 8 + b] + bF;
      float gg = gsc[64 + uu * 8 + b] + bG;
      float go = gsc[96 + uu * 8 + b] + bO;
      float iv = sigm(gi), fv = sigm(gf), ov = sigm(go), gv = tanhf(gg);
      c_reg = fv * c_reg + iv * gv;
      float hval = ov * tanhf(c_reg);
      int bglob = bg * 8 + b, unit = ug * 4 + uu;
      float* hd = hbuf + ((t & 1) << 14) + (bglob << 9) + unit;
      stg1fs(hd, hval);
      if (t == len) lasth[(bglob << 9) + unit] = hval;
    }
    if (tid < 64) {
      asm volatile("s_waitcnt vmcnt(0)" ::: "memory");   // wave0 stores at LLC
      if (tid == 0)
        __hip_atomic_fetch_add(mycnt, 1u, __ATOMIC_RELAXED, __HIP_MEMORY_SCOPE_AGENT);
    }
  }
}

// =====================================================================
// FC head
// =====================================================================
__global__ void __launch_bounds__(128)
fc_kernel(const float* __restrict__ lasth, const float* __restrict__ fcW,
          const float* __restrict__ fcb, float* __restrict__ out)
{
  int tid = threadIdx.x;
  int b = tid >> 2, n = tid & 3;
  const float4* h4 = (const float4*)(lasth + (size_t)b * 512);
  const float4* w4 = (const float4*)(fcW + (size_t)n * 512);
  float s0 = 0.f, s1 = 0.f, s2 = 0.f, s3 = 0.f;
#pragma unroll 8
  for (int k = 0; k < 128; ++k) {
    float4 a = h4[k], c = w4[k];
    s0 += a.x * c.x; s1 += a.y * c.y; s2 += a.z * c.z; s3 += a.w * c.w;
  }
  out[b * 4 + n] = fcb[n] + ((s0 + s1) + (s2 + s3));
}

// =====================================================================
// Fallback: round-2 proven persistent kernel (only if ws too small)
// =====================================================================
__device__ __forceinline__ void gl2lds16(const void* gsrc, void* ldst) {
  __builtin_amdgcn_global_load_lds(
      (const __attribute__((address_space(1))) u32*)gsrc,
      (__attribute__((address_space(3))) u32*)ldst, 16, 0, 0);
}

__global__ void __launch_bounds__(256)
lstm_persist(const int* __restrict__ xidx, const int* __restrict__ attn,
             const float* __restrict__ emb,
             const float* __restrict__ Wih, const float* __restrict__ Whh,
             const float* __restrict__ bih, const float* __restrict__ bhh,
             float* __restrict__ hbuf, float* __restrict__ lasth,
             u32* __restrict__ arrive)
{
  __shared__ __align__(16) float Wl[8][1024];
  __shared__ __align__(16) float ul[2][32][64];
  __shared__ float gsc[32][8];

  const int tid  = threadIdx.x;
  const int wg   = blockIdx.x;
  const int lane = tid & 63;
  const int wv   = tid >> 6;
  const int r    = tid & 7;
  const int bb   = tid >> 3;
  const int brl  = bb & 7;

#pragma unroll 2
  for (int i = 0; i < 8; ++i) {
    int ci = i * 256 + tid;
    int rr = ci >> 8;
    int cc = ci & 255;
    int R  = ((rr >> 1) << 9) + (wg * 2 + (rr & 1));
    const float* src = (cc < 128) ? (Wih + (size_t)R * 512 + cc * 4)
                                  : (Whh + (size_t)R * 512 + (cc - 128) * 4);
    float4 v = *(const float4*)src;
    int slot = cc ^ (rr & 7);
    *(float4*)&Wl[rr][slot * 4] = v;
  }
  float bias;
  {
    int R = ((r >> 1) << 9) + (wg * 2 + (r & 1));
    bias = bih[R] + bhh[R];
  }
  {
    int pb = tid >> 3, pc = tid & 7;
    const int4* ap = (const int4*)(attn + pb * 2048 + pc * 256);
    int s = 0;
#pragma unroll 8
    for (int k = 0; k < 64; ++k) { int4 a = ap[k]; s += a.x + a.y + a.z + a.w; }
    gsc[pb][pc] = (float)s;
  }
  __syncthreads();
  int   len_reg = 0;
  float c_reg   = 0.f;
  if (tid < 64) {
    int b2 = tid & 31;
    int s = 0;
#pragma unroll
    for (int k = 0; k < 8; ++k) s += (int)gsc[b2][k];
    len_reg = s - 1;
    if (len_reg < 0) len_reg = 2047;
  }
  __syncthreads();

  const int idx_b = 8 * wv + (lane & 7);
  int idx_cur = xidx[(size_t)idx_b * 2048];

  for (int t = 0; t < T_SEQ; ++t) {
    int idx_next = (t < T_SEQ - 1) ? xidx[(size_t)idx_b * 2048 + t + 1] : 0;
    float a0 = bias, a1 = 0.f, a2 = 0.f, a3 = 0.f;
    const float* hsrc = hbuf + (((t + 1) & 1) << 14);

    auto stageE = [&](int jt, int buf) {
#pragma unroll
      for (int q = 0; q < 2; ++q) {
        int rlq = 4 * q + (lane >> 4);
        int sc = lane & 15;
        int kc = sc ^ (rlq & 7);
        int rowg = __shfl(idx_cur, rlq, 64);
        const float* g = emb + (size_t)rowg * 512 + jt * 64 + kc * 4;
        gl2lds16(g, (void*)&ul[buf][8 * wv + 4 * q][0]);
      }
    };
    auto stageH = [&](int jt, int buf) {
#pragma unroll
      for (int q = 0; q < 2; ++q) {
        int rlq = 4 * q + (lane >> 4);
        int sc = lane & 15;
        int kc = sc ^ (rlq & 7);
        int blq = 8 * wv + rlq;
        const float* g = hsrc + (size_t)blq * 512 + jt * 64 + kc * 4;
        gl2lds16(g, (void*)&ul[buf][8 * wv + 4 * q][0]);
      }
    };
    auto computeT = [&](int jg, int buf) {
#pragma unroll
      for (int kc = 0; kc < 16; ++kc) {
        float4 uv4 = *(const float4*)&ul[buf][bb][(kc ^ brl) * 4];
        float4 wv4 = *(const float4*)&Wl[r][(((jg << 4) + kc) ^ r) * 4];
        a0 += uv4.x * wv4.x; a1 += uv4.y * wv4.y;
        a2 += uv4.z * wv4.z; a3 += uv4.w * wv4.w;
      }
    };

    stageE(0, 0);
#pragma unroll
    for (int jt = 0; jt < 8; ++jt) {
      if (jt < 7) { stageE(jt + 1, (jt + 1) & 1); asm volatile("s_waitcnt vmcnt(2)" ::: "memory"); }
      else       { asm volatile("s_waitcnt vmcnt(0)" ::: "memory"); }
      computeT(jt, jt & 1);
    }

    if (tid == 0) {
      u32 target = (u32)t << 8;
      while (__hip_atomic_load(arrive, __ATOMIC_RELAXED, __HIP_MEMORY_SCOPE_AGENT) < target)
        __builtin_amdgcn_s_sleep(2);
    }
    __syncthreads();
    __builtin_amdgcn_fence(__ATOMIC_ACQUIRE, "agent");

    stageH(0, 0);
#pragma unroll
    for (int jt = 0; jt < 8; ++jt) {
      if (jt < 7) { stageH(jt + 1, (jt + 1) & 1); asm volatile("s_waitcnt vmcnt(2)" ::: "memory"); }
      else       { asm volatile("s_waitcnt vmcnt(0)" ::: "memory"); }
      computeT(8 + jt, jt & 1);
    }

    gsc[bb][r] = a0 + a1 + a2 + a3;
    __syncthreads();
    if (tid < 64) {
      int u  = tid >> 5;
      int b2 = tid & 31;
      float gi = gsc[b2][u];
      float gf = gsc[b2][2 + u];
      float gg = gsc[b2][4 + u];
      float go = gsc[b2][6 + u];
      float iv = sigm(gi), fv = sigm(gf), ov = sigm(go);
      float gv = tanhf(gg);
      c_reg = fv * c_reg + iv * gv;
      float hv = ov * tanhf(c_reg);
      int unit = (wg << 1) + u;
      hbuf[((t & 1) << 14) + (b2 << 9) + unit] = hv;
      if (t == len_reg) lasth[(b2 << 9) + unit] = hv;
      __builtin_amdgcn_fence(__ATOMIC_RELEASE, "agent");
      if (tid == 0)
        __hip_atomic_fetch_add(arrive, 1u, __ATOMIC_RELAXED, __HIP_MEMORY_SCOPE_AGENT);
    }
    idx_cur = idx_next;
  }
}

extern "C" void kernel_launch(void* const* d_in, const int* in_sizes, int n_in,
                              void* d_out, int out_size, void* d_ws, size_t ws_size,
                              hipStream_t stream) {
  const int*   x    = (const int*)d_in[0];
  const int*   attn = (const int*)d_in[1];
  const float* emb  = (const float*)d_in[2];
  const float* Wih  = (const float*)d_in[3];
  const float* Whh  = (const float*)d_in[4];
  const float* bih  = (const float*)d_in[5];
  const float* bhh  = (const float*)d_in[6];
  const float* fcW  = (const float*)d_in[7];
  const float* fcb  = (const float*)d_in[8];
  float* out = (float*)d_out;
  char* ws = (char*)d_ws;

  if (ws_size >= WS_NEED) {
    float* hbuf  = (float*)(ws + OFF_HBUF);
    u32*   cnts  = (u32*)(ws + OFF_CNT);
    float* lasth = (float*)(ws + OFF_LASTH);

    (void)hipMemsetAsync(ws, 0, OFF_LASTH, stream);   // hbuf + counters

    hipLaunchKernelGGL(lstm_seq, dim3(NWG), dim3(256), 0, stream,
                       x, attn, emb, Wih, Whh, bih, bhh, hbuf, cnts, lasth);
    hipLaunchKernelGGL(fc_kernel, dim3(1), dim3(128), 0, stream,
                       lasth, fcW, fcb, out);
  } else {
    float* hbuf   = (float*)(ws + FB_OFF_HBUF);
    u32*   arrive = (u32*)(ws + FB_OFF_ARRIVE);
    float* lasth  = (float*)(ws + FB_OFF_LASTH);
    (void)hipMemsetAsync(ws, 0, 131072 + 256, stream);
    hipLaunchKernelGGL(lstm_persist, dim3(256), dim3(256), 0, stream,
                       x, attn, emb, Wih, Whh, bih, bhh, hbuf, lasth, arrive);
    hipLaunchKernelGGL(fc_kernel, dim3(1), dim3(128), 0, stream,
                       lasth, fcW, fcb, out);
  }
}

// Round 14
// 19560.506 us; speedup vs baseline: 2.0795x; 1.2030x over previous
//
#include <hip/hip_runtime.h>
#include <math.h>

typedef unsigned int u32;

#define T_SEQ   2048
#define NWG     256

// ---------------- workspace layout (bytes) ----------------
#define OFF_HBUF   0            // float[2][32][512] = 131072
#define OFF_CNT    131072       // u32[8][8][32] (8 bg x 8 sub-counters 128B apart) = 8192
#define OFF_LASTH  139264       // float[32][512] = 65536
#define WS_NEED    204800ull

// ---------------- fallback (round-2 proven) layout ----------------
#define FB_OFF_HBUF   0
#define FB_OFF_ARRIVE 131072
#define FB_OFF_LASTH  131328

#define DYN_LDS_BYTES 140288    // Wl 131072 + Hl 8192 + gsc 1024

__device__ __forceinline__ float sigm(float x) { return 1.0f / (1.0f + expf(-x)); }

// ---- LLC-coherent accessors (sc0 sc1 = bypass L1 + XCD L2); r8/r10-proven ----
__device__ __forceinline__ float4 ldg4s(const float* p) {
  float4 v;
  asm volatile("global_load_dwordx4 %0, %1, off sc0 sc1" : "=v"(v) : "v"(p) : "memory");
  return v;
}
__device__ __forceinline__ void stg1fs(float* p, float v) {
  asm volatile("global_store_dword %0, %1, off sc0 sc1" :: "v"(p), "v"(v) : "memory");
}

// =====================================================================
// Sequential LSTM v9: 256 WGs x 256 threads, 1 WG/CU (140 KB dyn LDS).
// HYPOTHESIS UNDER TEST: per-step cost scales with sync-group size
// (r10: 64 producers = 13.6ms; r13: 128 = 23.3ms). v9 shrinks to 32.
// ug = bid>>3 owns 16 units (64 gate rows); bg = bid&7 owns 4 batches.
// Whh slice (64 rows x 512 = 128 KB) in LDS, XOR-swizzled (b128 floor).
// Wih slice streamed from L2 per step (pre-barrier, overlappable) --
// only the post-barrier h-phase is latency-critical and that uses LDS.
// Lane map: rr = lane>>4 owns rows {rr,rr+4,rr+8,rr+12}; kq = lane&15,
// k-slice = 32 floats (8 float4). Wave = gate. acc[4 rows][4 b].
// Reduction: 4x shfl_xor (kq bits 0..3), 16 writes from kq==0 lanes.
// Sync: 8 sub-counters/bg 128B apart (r12/13-proven shape), 32
// producers, target 4t; h via sc0sc1 + vmcnt(0) drain before post.
// Watchdog: poll caps -> sticky dead -> free-run (no hang).
// =====================================================================
__global__ void __launch_bounds__(256, 1)
lstm_seq(const int* __restrict__ x, const int* __restrict__ attn,
         const float* __restrict__ emb,
         const float* __restrict__ Wih, const float* __restrict__ Whh,
         const float* __restrict__ bih, const float* __restrict__ bhh,
         float* __restrict__ hbuf, u32* __restrict__ counters,
         float* __restrict__ lasth)
{
  extern __shared__ __align__(16) char smem[];
  float4* Wl4 = (float4*)smem;                       // [64 rows][128 chunks] swizzled
  float4* Hl4 = (float4*)(smem + 131072);            // [4 b][128 chunks] swizzled
  float*  gsc = (float*)(smem + 131072 + 8192);      // [4 gates][16 uu][4 b]
  __shared__ int s_dead;

  const int tid = threadIdx.x, bid = blockIdx.x;
  const int ug = bid >> 3, bg = bid & 7;
  const int wv = tid >> 6, lane = tid & 63;
  const int rr = lane >> 4, kq = lane & 15;

  u32* cntb  = counters + bg * 256;                  // 8 sub-counters, 128B apart
  u32* mycnt = cntb + (ug & 7) * 32;

  // ---- Whh slice -> LDS, swizzled (one-time) ----
  // row r = gate*16 + uu ; chunk c stored at (c&~7)|(((c&7)+((c>>3)&7)+r)&7)
#pragma unroll
  for (int k = 0; k < 32; ++k) {
    int cf = tid + k * 256;            // 0..8191
    int r = cf >> 7, c = cf & 127;
    int R = (r >> 4) * 512 + ug * 16 + (r & 15);
    float4 v = *(const float4*)(Whh + (size_t)R * 512 + c * 4);
    int pos = r * 128 + (c & ~7) + (((c & 7) + ((c >> 3) & 7) + r) & 7);
    Wl4[pos] = v;
  }

  // ---- lengths (partials in gsc as [64 chunks][4 b]) ----
  {
    int b = tid & 3, c = tid >> 2;     // c in [0,64)
    const int4* ap = (const int4*)(attn + (size_t)(bg * 4 + b) * 2048 + c * 32);
    int s = 0;
#pragma unroll
    for (int k = 0; k < 8; ++k) { int4 a = ap[k]; s += a.x + a.y + a.z + a.w; }
    gsc[c * 4 + b] = (float)s;
  }
  if (tid == 0) s_dead = 0;
  __syncthreads();
  int len = 0; float c_reg = 0.f;
  float bI = 0, bF = 0, bG = 0, bO = 0;
  if (tid < 64) {
    int b = tid >> 4, uu = tid & 15;   // b slow, uu fast (store coalescing)
    int s = 0;
#pragma unroll
    for (int c = 0; c < 64; ++c) s += (int)gsc[c * 4 + b];
    len = s - 1; if (len < 0) len = T_SEQ - 1;
    int gu = ug * 16 + uu;
    bI = bih[gu]        + bhh[gu];
    bF = bih[512 + gu]  + bhh[512 + gu];
    bG = bih[1024 + gu] + bhh[1024 + gu];
    bO = bih[1536 + gu] + bhh[1536 + gu];
  }
  __syncthreads();   // gsc reusable

  bool dead = false;

  for (int t = 0; t < T_SEQ; ++t) {
    float acc[4][4];
#pragma unroll
    for (int i = 0; i < 4; ++i) { acc[i][0] = 0.f; acc[i][1] = 0.f; acc[i][2] = 0.f; acc[i][3] = 0.f; }

    // ---- emb phase: Wih streamed from L2, emb cached (pre-barrier) ----
    int xr[4];
#pragma unroll
    for (int b = 0; b < 4; ++b) xr[b] = x[(size_t)(bg * 4 + b) * 2048 + t];
#pragma unroll
    for (int q = 0; q < 8; ++q) {
      float4 w4[4], ev[4];
#pragma unroll
      for (int i = 0; i < 4; ++i) {
        int R = wv * 512 + ug * 16 + rr + 4 * i;
        w4[i] = *(const float4*)(Wih + (size_t)R * 512 + kq * 32 + q * 4);
      }
#pragma unroll
      for (int b = 0; b < 4; ++b)
        ev[b] = *(const float4*)(emb + (size_t)xr[b] * 512 + kq * 32 + q * 4);
#pragma unroll
      for (int i = 0; i < 4; ++i)
#pragma unroll
        for (int b = 0; b < 4; ++b) {
          acc[i][b] += w4[i].x * ev[b].x; acc[i][b] += w4[i].y * ev[b].y;
          acc[i][b] += w4[i].z * ev[b].z; acc[i][b] += w4[i].w * ev[b].w;
        }
    }

    // ---- barrier: lanes 0..7 poll the 8 sub-counters (target 4t) ----
    if (tid < 8 && !dead) {
      const u32 target = (u32)(t << 2);
      const u32* myc = cntb + tid * 32;
      int it = 0;
      while (true) {
        u32 v = __hip_atomic_load(myc, __ATOMIC_RELAXED, __HIP_MEMORY_SCOPE_AGENT);
        if (__all((int)v >= (int)target)) break;
        if (++it > (1 << 17)) { s_dead = 1; break; }   // watchdog: no hang
        __builtin_amdgcn_s_sleep(1);
      }
    }
    __syncthreads();
    if (s_dead) dead = true;

    // ---- h stage: 2 coalesced sc0sc1 float4/thread -> swizzled Hl ----
    {
      const float* hsrc = hbuf + (((t + 1) & 1) << 14) + (size_t)(bg * 4) * 512;
      float4 hv[2];
      int pp[2];
#pragma unroll
      for (int k = 0; k < 2; ++k) {
        int cf = tid + k * 256;        // 0..511
        int b = cf >> 7, cc = cf & 127;
        hv[k] = ldg4s(hsrc + (size_t)b * 512 + cc * 4);
        pp[k] = b * 128 + (cc & ~7) + (((cc & 7) + ((cc >> 3) & 7) + b) & 7);
      }
      asm volatile("s_waitcnt vmcnt(0)" ::: "memory");
      __builtin_amdgcn_sched_barrier(0);
#pragma unroll
      for (int k = 0; k < 2; ++k) Hl4[pp[k]] = hv[k];
    }
    __syncthreads();

    // ---- h phase: Whh from swizzled LDS, h from swizzled Hl ----
#pragma unroll
    for (int q = 0; q < 8; ++q) {
      float4 w4[4], hv4[4];
#pragma unroll
      for (int i = 0; i < 4; ++i) {
        int r = wv * 16 + rr + 4 * i;
        w4[i] = Wl4[r * 128 + kq * 8 + ((q + (kq & 7) + r) & 7)];
      }
#pragma unroll
      for (int b = 0; b < 4; ++b)
        hv4[b] = Hl4[b * 128 + kq * 8 + ((q + (kq & 7) + b) & 7)];
#pragma unroll
      for (int i = 0; i < 4; ++i)
#pragma unroll
        for (int b = 0; b < 4; ++b) {
          acc[i][b] += w4[i].x * hv4[b].x; acc[i][b] += w4[i].y * hv4[b].y;
          acc[i][b] += w4[i].z * hv4[b].z; acc[i][b] += w4[i].w * hv4[b].w;
        }
    }

    // ---- k-reduction: 4x shfl_xor over kq (lane bits 0..3) ----
#pragma unroll
    for (int i = 0; i < 4; ++i)
#pragma unroll
      for (int b = 0; b < 4; ++b) {
        float v = acc[i][b];
        v += __shfl_xor(v, 1, 64);
        v += __shfl_xor(v, 2, 64);
        v += __shfl_xor(v, 4, 64);
        v += __shfl_xor(v, 8, 64);
        acc[i][b] = v;
      }
    if (kq == 0) {                     // 4 lanes/wave publish 16 values each
#pragma unroll
      for (int i = 0; i < 4; ++i)
#pragma unroll
        for (int b = 0; b < 4; ++b)
          gsc[wv * 64 + (rr + 4 * i) * 4 + b] = acc[i][b];
    }
    __syncthreads();

    // ---- activations + sc0sc1 h post (wave 0), then sub-counter post ----
    if (tid < 64) {
      int b = tid >> 4, uu = tid & 15;
      float gi = gsc[  0 + uu * 4 + b] + bI;
      float gf = gsc[ 64 + uu * 4 + b] + bF;
      float gg = gsc[128 + uu * 4 + b] + bG;
      float go = gsc[192 + uu * 4 + b] + bO;
      float iv = sigm(gi), fv = sigm(gf), ov = sigm(go), gv = tanhf(gg);
      c_reg = fv * c_reg + iv * gv;
      float hval = ov * tanhf(c_reg);
      int bglob = bg * 4 + b, unit = ug * 16 + uu;
      float* hd = hbuf + ((t & 1) << 14) + (bglob << 9) + unit;
      stg1fs(hd, hval);
      if (t == len) lasth[(bglob << 9) + unit] = hval;
      asm volatile("s_waitcnt vmcnt(0)" ::: "memory");   // wave0 stores at LLC
      if (tid == 0)
        __hip_atomic_fetch_add(mycnt, 1u, __ATOMIC_RELAXED, __HIP_MEMORY_SCOPE_AGENT);
    }
  }
}

// =====================================================================
// FC head
// =====================================================================
__global__ void __launch_bounds__(128)
fc_kernel(const float* __restrict__ lasth, const float* __restrict__ fcW,
          const float* __restrict__ fcb, float* __restrict__ out)
{
  int tid = threadIdx.x;
  int b = tid >> 2, n = tid & 3;
  const float4* h4 = (const float4*)(lasth + (size_t)b * 512);
  const float4* w4 = (const float4*)(fcW + (size_t)n * 512);
  float s0 = 0.f, s1 = 0.f, s2 = 0.f, s3 = 0.f;
#pragma unroll 8
  for (int k = 0; k < 128; ++k) {
    float4 a = h4[k], c = w4[k];
    s0 += a.x * c.x; s1 += a.y * c.y; s2 += a.z * c.z; s3 += a.w * c.w;
  }
  out[b * 4 + n] = fcb[n] + ((s0 + s1) + (s2 + s3));
}

// =====================================================================
// Fallback: round-2 proven persistent kernel (only if ws too small)
// =====================================================================
__device__ __forceinline__ void gl2lds16(const void* gsrc, void* ldst) {
  __builtin_amdgcn_global_load_lds(
      (const __attribute__((address_space(1))) u32*)gsrc,
      (__attribute__((address_space(3))) u32*)ldst, 16, 0, 0);
}

__global__ void __launch_bounds__(256)
lstm_persist(const int* __restrict__ xidx, const int* __restrict__ attn,
             const float* __restrict__ emb,
             const float* __restrict__ Wih, const float* __restrict__ Whh,
             const float* __restrict__ bih, const float* __restrict__ bhh,
             float* __restrict__ hbuf, float* __restrict__ lasth,
             u32* __restrict__ arrive)
{
  __shared__ __align__(16) float Wl[8][1024];
  __shared__ __align__(16) float ul[2][32][64];
  __shared__ float gsc[32][8];

  const int tid  = threadIdx.x;
  const int wg   = blockIdx.x;
  const int lane = tid & 63;
  const int wv   = tid >> 6;
  const int r    = tid & 7;
  const int bb   = tid >> 3;
  const int brl  = bb & 7;

#pragma unroll 2
  for (int i = 0; i < 8; ++i) {
    int ci = i * 256 + tid;
    int rr = ci >> 8;
    int cc = ci & 255;
    int R  = ((rr >> 1) << 9) + (wg * 2 + (rr & 1));
    const float* src = (cc < 128) ? (Wih + (size_t)R * 512 + cc * 4)
                                  : (Whh + (size_t)R * 512 + (cc - 128) * 4);
    float4 v = *(const float4*)src;
    int slot = cc ^ (rr & 7);
    *(float4*)&Wl[rr][slot * 4] = v;
  }
  float bias;
  {
    int R = ((r >> 1) << 9) + (wg * 2 + (r & 1));
    bias = bih[R] + bhh[R];
  }
  {
    int pb = tid >> 3, pc = tid & 7;
    const int4* ap = (const int4*)(attn + pb * 2048 + pc * 256);
    int s = 0;
#pragma unroll 8
    for (int k = 0; k < 64; ++k) { int4 a = ap[k]; s += a.x + a.y + a.z + a.w; }
    gsc[pb][pc] = (float)s;
  }
  __syncthreads();
  int   len_reg = 0;
  float c_reg   = 0.f;
  if (tid < 64) {
    int b2 = tid & 31;
    int s = 0;
#pragma unroll
    for (int k = 0; k < 8; ++k) s += (int)gsc[b2][k];
    len_reg = s - 1;
    if (len_reg < 0) len_reg = 2047;
  }
  __syncthreads();

  const int idx_b = 8 * wv + (lane & 7);
  int idx_cur = xidx[(size_t)idx_b * 2048];

  for (int t = 0; t < T_SEQ; ++t) {
    int idx_next = (t < T_SEQ - 1) ? xidx[(size_t)idx_b * 2048 + t + 1] : 0;
    float a0 = bias, a1 = 0.f, a2 = 0.f, a3 = 0.f;
    const float* hsrc = hbuf + (((t + 1) & 1) << 14);

    auto stageE = [&](int jt, int buf) {
#pragma unroll
      for (int q = 0; q < 2; ++q) {
        int rlq = 4 * q + (lane >> 4);
        int sc = lane & 15;
        int kc = sc ^ (rlq & 7);
        int rowg = __shfl(idx_cur, rlq, 64);
        const float* g = emb + (size_t)rowg * 512 + jt * 64 + kc * 4;
        gl2lds16(g, (void*)&ul[buf][8 * wv + 4 * q][0]);
      }
    };
    auto stageH = [&](int jt, int buf) {
#pragma unroll
      for (int q = 0; q < 2; ++q) {
        int rlq = 4 * q + (lane >> 4);
        int sc = lane & 15;
        int kc = sc ^ (rlq & 7);
        int blq = 8 * wv + rlq;
        const float* g = hsrc + (size_t)blq * 512 + jt * 64 + kc * 4;
        gl2lds16(g, (void*)&ul[buf][8 * wv + 4 * q][0]);
      }
    };
    auto computeT = [&](int jg, int buf) {
#pragma unroll
      for (int kc = 0; kc < 16; ++kc) {
        float4 uv4 = *(const float4*)&ul[buf][bb][(kc ^ brl) * 4];
        float4 wv4 = *(const float4*)&Wl[r][(((jg << 4) + kc) ^ r) * 4];
        a0 += uv4.x * wv4.x; a1 += uv4.y * wv4.y;
        a2 += uv4.z * wv4.z; a3 += uv4.w * wv4.w;
      }
    };

    stageE(0, 0);
#pragma unroll
    for (int jt = 0; jt < 8; ++jt) {
      if (jt < 7) { stageE(jt + 1, (jt + 1) & 1); asm volatile("s_waitcnt vmcnt(2)" ::: "memory"); }
      else       { asm volatile("s_waitcnt vmcnt(0)" ::: "memory"); }
      computeT(jt, jt & 1);
    }

    if (tid == 0) {
      u32 target = (u32)t << 8;
      while (__hip_atomic_load(arrive, __ATOMIC_RELAXED, __HIP_MEMORY_SCOPE_AGENT) < target)
        __builtin_amdgcn_s_sleep(2);
    }
    __syncthreads();
    __builtin_amdgcn_fence(__ATOMIC_ACQUIRE, "agent");

    stageH(0, 0);
#pragma unroll
    for (int jt = 0; jt < 8; ++jt) {
      if (jt < 7) { stageH(jt + 1, (jt + 1) & 1); asm volatile("s_waitcnt vmcnt(2)" ::: "memory"); }
      else       { asm volatile("s_waitcnt vmcnt(0)" ::: "memory"); }
      computeT(8 + jt, jt & 1);
    }

    gsc[bb][r] = a0 + a1 + a2 + a3;
    __syncthreads();
    if (tid < 64) {
      int u  = tid >> 5;
      int b2 = tid & 31;
      float gi = gsc[b2][u];
      float gf = gsc[b2][2 + u];
      float gg = gsc[b2][4 + u];
      float go = gsc[b2][6 + u];
      float iv = sigm(gi), fv = sigm(gf), ov = sigm(go);
      float gv = tanhf(gg);
      c_reg = fv * c_reg + iv * gv;
      float hv = ov * tanhf(c_reg);
      int unit = (wg << 1) + u;
      hbuf[((t & 1) << 14) + (b2 << 9) + unit] = hv;
      if (t == len_reg) lasth[(b2 << 9) + unit] = hv;
      __builtin_amdgcn_fence(__ATOMIC_RELEASE, "agent");
      if (tid == 0)
        __hip_atomic_fetch_add(arrive, 1u, __ATOMIC_RELAXED, __HIP_MEMORY_SCOPE_AGENT);
    }
    idx_cur = idx_next;
  }
}

extern "C" void kernel_launch(void* const* d_in, const int* in_sizes, int n_in,
                              void* d_out, int out_size, void* d_ws, size_t ws_size,
                              hipStream_t stream) {
  const int*   x    = (const int*)d_in[0];
  const int*   attn = (const int*)d_in[1];
  const float* emb  = (const float*)d_in[2];
  const float* Wih  = (const float*)d_in[3];
  const float* Whh  = (const float*)d_in[4];
  const float* bih  = (const float*)d_in[5];
  const float* bhh  = (const float*)d_in[6];
  const float* fcW  = (const float*)d_in[7];
  const float* fcb  = (const float*)d_in[8];
  float* out = (float*)d_out;
  char* ws = (char*)d_ws;

  if (ws_size >= WS_NEED) {
    float* hbuf  = (float*)(ws + OFF_HBUF);
    u32*   cnts  = (u32*)(ws + OFF_CNT);
    float* lasth = (float*)(ws + OFF_LASTH);

    (void)hipFuncSetAttribute((const void*)lstm_seq,
                              hipFuncAttributeMaxDynamicSharedMemorySize, DYN_LDS_BYTES);
    (void)hipMemsetAsync(ws, 0, OFF_LASTH, stream);   // hbuf + counters

    hipLaunchKernelGGL(lstm_seq, dim3(NWG), dim3(256), DYN_LDS_BYTES, stream,
                       x, attn, emb, Wih, Whh, bih, bhh, hbuf, cnts, lasth);
    hipLaunchKernelGGL(fc_kernel, dim3(1), dim3(128), 0, stream,
                       lasth, fcW, fcb, out);
  } else {
    float* hbuf   = (float*)(ws + FB_OFF_HBUF);
    u32*   arrive = (u32*)(ws + FB_OFF_ARRIVE);
    float* lasth  = (float*)(ws + FB_OFF_LASTH);
    (void)hipMemsetAsync(ws, 0, 131072 + 256, stream);
    hipLaunchKernelGGL(lstm_persist, dim3(256), dim3(256), 0, stream,
                       x, attn, emb, Wih, Whh, bih, bhh, hbuf, lasth, arrive);
    hipLaunchKernelGGL(fc_kernel, dim3(1), dim3(128), 0, stream,
                       lasth, fcW, fcb, out);
  }
}

// Round 15
// 13700.337 us; speedup vs baseline: 2.9690x; 1.4277x over previous
//
#include <hip/hip_runtime.h>
#include <math.h>

typedef unsigned int u32;

#define T_SEQ   2048
#define NWG     256

// ---------------- workspace layout (bytes) ----------------
#define OFF_HBUF   0            // float[2][32][512] = 131072
#define OFF_CNT    131072       // u32[4][64] (4 counters, 256B apart) = 1024 (2048 resv)
#define OFF_LASTH  133120       // float[32][512] = 65536
#define WS_NEED    198656ull

// ---------------- fallback (round-2 proven) layout ----------------
#define FB_OFF_HBUF   0
#define FB_OFF_ARRIVE 131072
#define FB_OFF_LASTH  131328

#define DYN_LDS_BYTES 148480    // Wl 131072 + Hl 16384 + gsc 1024

__device__ __forceinline__ float sigm(float x) { return 1.0f / (1.0f + expf(-x)); }

// ---- LLC-coherent accessors (sc0 sc1 = bypass L1 + XCD L2); r8/r10-proven ----
__device__ __forceinline__ float4 ldg4s(const float* p) {
  float4 v;
  asm volatile("global_load_dwordx4 %0, %1, off sc0 sc1" : "=v"(v) : "v"(p) : "memory");
  return v;
}
__device__ __forceinline__ void stg1fs(float* p, float v) {
  asm volatile("global_store_dword %0, %1, off sc0 sc1" :: "v"(p), "v"(v) : "memory");
}

// =====================================================================
// Sequential LSTM v11: r10's EXACT partition + protocol (13.6 ms,
// passed), upgraded to 512-thread WGs -> 2 waves/SIMD inside one WG.
// Rationale: r10 at 1 wave/SIMD exposes every ds_read/global latency in
// the serial phase chain; W-in-LDS is shared by the whole WG, so wider
// WGs add TLP without duplicating W (the constraint that sank r12-r14).
// ug = bid>>2 owns 8 units -> 32 gate rows (r = g*8+uu); bg = bid&3
// owns 8 batches. Wl[32][1024] f32 = 128 KB LDS, r10 swizzle.
// Wave wv: rgrp = wv>>1 (rows rgrp*8..+8), bh = wv&1 (batches bh*4..+4).
// Lane: kg = lane>>2 (k-slice 32 floats/phase), inner = lane&3
// (rows inner, inner+4 within the quarter). acc[2][4]; 512 FMA/thread.
// Reduction: 4x shfl_xor over kg, kg==0 lanes publish to gsc[r][b].
// Sync: ONE monotone counter per bg (256B apart), target 64t — r10's.
// h: sc0sc1 + vmcnt(0) drain before post. Watchdog -> no hang.
// =====================================================================
__global__ void __launch_bounds__(512, 1)
lstm_seq(const int* __restrict__ x, const int* __restrict__ attn,
         const float* __restrict__ emb,
         const float* __restrict__ Wih, const float* __restrict__ Whh,
         const float* __restrict__ bih, const float* __restrict__ bhh,
         float* __restrict__ hbuf, u32* __restrict__ counters,
         float* __restrict__ lasth)
{
  extern __shared__ __align__(16) char smem[];
  float4* Wl4 = (float4*)smem;                       // [32 rows][256 chunks] swizzled
  float4* Hl4 = (float4*)(smem + 131072);            // [8 b][128 chunks] swizzled
  float*  gsc = (float*)(smem + 131072 + 16384);     // [32 rows][8 b]
  __shared__ int s_dead;

  const int tid = threadIdx.x, bid = blockIdx.x;
  const int ug = bid >> 2, bg = bid & 3;
  const int wv = tid >> 6, lane = tid & 63;
  const int rgrp = wv >> 1;                          // row quarter 0..3
  const int bh   = wv & 1;                           // batch half
  const int kg   = lane >> 2;                        // k-slice 0..15
  const int inner = lane & 3;                        // row-in-quarter base

  u32* cnt = counters + bg * 64;                     // 256B-padded per-bg counter

  // ---- W slice -> LDS, swizzled (one-time; r10 formula) ----
#pragma unroll
  for (int k = 0; k < 16; ++k) {
    int cf = tid + k * 512;            // 0..8191
    int r  = cf >> 8, c = cf & 255;
    int R  = (r >> 3) * 512 + ug * 8 + (r & 7);      // gate*512 + unit
    const float* src = (c < 128) ? (Wih + (size_t)R * 512 + c * 4)
                                 : (Whh + (size_t)R * 512 + (c - 128) * 4);
    float4 v = *(const float4*)src;
    int p = r * 256 + (c & ~7) + (((c & 7) + ((c >> 3) & 15) + (r >> 2)) & 7);
    Wl4[p] = v;
  }

  // ---- lengths (partials in Hl scratch: [64 chunks][8 b]) ----
  {
    float* scratch = (float*)Hl4;
    int b = tid & 7, c = tid >> 3;     // c in [0,64)
    const int4* ap = (const int4*)(attn + (size_t)(bg * 8 + b) * 2048 + c * 32);
    int s = 0;
#pragma unroll
    for (int k = 0; k < 8; ++k) { int4 a = ap[k]; s += a.x + a.y + a.z + a.w; }
    scratch[c * 8 + b] = (float)s;
  }
  if (tid == 0) s_dead = 0;
  __syncthreads();
  int len = 0; float c_reg = 0.f;
  float bI = 0, bF = 0, bG = 0, bO = 0;
  if (tid < 64) {
    const float* scratch = (const float*)Hl4;
    int b = tid & 7, uu = tid >> 3;    // unit 0..7
    int s = 0;
#pragma unroll
    for (int c = 0; c < 64; ++c) s += (int)scratch[c * 8 + b];
    len = s - 1; if (len < 0) len = T_SEQ - 1;
    int gu = ug * 8 + uu;
    bI = bih[gu]        + bhh[gu];
    bF = bih[512 + gu]  + bhh[512 + gu];
    bG = bih[1024 + gu] + bhh[1024 + gu];
    bO = bih[1536 + gu] + bhh[1536 + gu];
  }
  __syncthreads();   // Hl scratch done

  bool dead = false;

  for (int t = 0; t < T_SEQ; ++t) {
    float acc[2][4];
#pragma unroll
    for (int i = 0; i < 2; ++i) { acc[i][0] = 0.f; acc[i][1] = 0.f; acc[i][2] = 0.f; acc[i][3] = 0.f; }

    // ---- W fragment, phase 0 (emb columns) ----
    float4 w[2][8];
#pragma unroll
    for (int i = 0; i < 2; ++i) {
      int r = rgrp * 8 + inner + 4 * i;
#pragma unroll
      for (int q = 0; q < 8; ++q)
        w[i][q] = Wl4[r * 256 + kg * 8 + ((q + kg + (r >> 2)) & 7)];
    }

    // ---- emb phase (h-independent; overlaps producer tail) ----
    int xr[4];
#pragma unroll
    for (int jb = 0; jb < 4; ++jb)
      xr[jb] = x[(size_t)(bg * 8 + bh * 4 + jb) * 2048 + t];
#pragma unroll
    for (int jb = 0; jb < 4; ++jb) {
      const float4* ep = (const float4*)(emb + (size_t)xr[jb] * 512 + kg * 32);
      float4 e[8];
#pragma unroll
      for (int q = 0; q < 8; ++q) e[q] = ep[q];
#pragma unroll
      for (int q = 0; q < 8; ++q)
#pragma unroll
        for (int i = 0; i < 2; ++i) {
          acc[i][jb] += w[i][q].x * e[q].x; acc[i][jb] += w[i][q].y * e[q].y;
          acc[i][jb] += w[i][q].z * e[q].z; acc[i][jb] += w[i][q].w * e[q].w;
        }
    }

    // ---- barrier: tid 0 polls the bg counter (r10-proven) ----
    if (tid == 0 && !dead) {
      int it = 0;
      const u32 target = (u32)(t << 6);              // 64 posts per step
      while (__hip_atomic_load(cnt, __ATOMIC_RELAXED, __HIP_MEMORY_SCOPE_AGENT) < target) {
        if (++it > (1 << 16)) { s_dead = 1; break; } // watchdog: no hang
        __builtin_amdgcn_s_sleep(4);
      }
    }
    __syncthreads();
    if (s_dead) dead = true;

    // ---- h stage: 2 coalesced sc0sc1 float4/thread -> swizzled Hl ----
    {
      const float* hsrc = hbuf + (((t + 1) & 1) << 14) + (size_t)(bg * 8) * 512;
      float4 hv[2];
      int pp[2];
#pragma unroll
      for (int k = 0; k < 2; ++k) {
        int cf = tid + k * 512;        // 0..1023
        int b = cf >> 7, c = cf & 127;
        hv[k] = ldg4s(hsrc + (size_t)b * 512 + c * 4);
        pp[k] = b * 128 + (c & ~7) + (((c & 7) + (c >> 3) + b) & 7);
      }
      asm volatile("s_waitcnt vmcnt(0)" ::: "memory");
      __builtin_amdgcn_sched_barrier(0);
#pragma unroll
      for (int k = 0; k < 2; ++k) Hl4[pp[k]] = hv[k];
    }
    __syncthreads();

    // ---- W fragment, phase 1 (h columns: +128 chunks, same swizzle) ----
#pragma unroll
    for (int i = 0; i < 2; ++i) {
      int r = rgrp * 8 + inner + 4 * i;
#pragma unroll
      for (int q = 0; q < 8; ++q)
        w[i][q] = Wl4[r * 256 + 128 + kg * 8 + ((q + kg + (r >> 2)) & 7)];
    }

    // ---- h phase: W from regs, u from swizzled Hl ----
#pragma unroll
    for (int jb = 0; jb < 4; ++jb) {
      int bl = bh * 4 + jb;
      float4 e[8];
#pragma unroll
      for (int q = 0; q < 8; ++q)
        e[q] = Hl4[bl * 128 + kg * 8 + ((q + kg + bl) & 7)];
#pragma unroll
      for (int q = 0; q < 8; ++q)
#pragma unroll
        for (int i = 0; i < 2; ++i) {
          acc[i][jb] += w[i][q].x * e[q].x; acc[i][jb] += w[i][q].y * e[q].y;
          acc[i][jb] += w[i][q].z * e[q].z; acc[i][jb] += w[i][q].w * e[q].w;
        }
    }

    // ---- k-reduction: 4x shfl_xor over kg (lane bits 2..5) ----
#pragma unroll
    for (int i = 0; i < 2; ++i)
#pragma unroll
      for (int jb = 0; jb < 4; ++jb) {
        float v = acc[i][jb];
        v += __shfl_xor(v, 4, 64);
        v += __shfl_xor(v, 8, 64);
        v += __shfl_xor(v, 16, 64);
        v += __shfl_xor(v, 32, 64);
        acc[i][jb] = v;
      }
    if (kg == 0) {                     // lanes 0..3 of each wave publish
#pragma unroll
      for (int i = 0; i < 2; ++i) {
        int r = rgrp * 8 + inner + 4 * i;
#pragma unroll
        for (int jb = 0; jb < 4; ++jb)
          gsc[r * 8 + bh * 4 + jb] = acc[i][jb];
      }
    }
    __syncthreads();

    // ---- activations + sc0sc1 h post (wave 0), then counter post ----
    if (tid < 64) {
      int b = tid & 7, uu = tid >> 3;
      float gi = gsc[(0  + uu) * 8 + b] + bI;
      float gf = gsc[(8  + uu) * 8 + b] + bF;
      float gg = gsc[(16 + uu) * 8 + b] + bG;
      float go = gsc[(24 + uu) * 8 + b] + bO;
      float iv = sigm(gi), fv = sigm(gf), ov = sigm(go), gv = tanhf(gg);
      c_reg = fv * c_reg + iv * gv;
      float hval = ov * tanhf(c_reg);
      int bglob = bg * 8 + b, unit = ug * 8 + uu;
      float* hd = hbuf + ((t & 1) << 14) + (bglob << 9) + unit;
      stg1fs(hd, hval);
      if (t == len) lasth[(bglob << 9) + unit] = hval;
      asm volatile("s_waitcnt vmcnt(0)" ::: "memory");   // wave0 stores at LLC
      if (tid == 0)
        __hip_atomic_fetch_add(cnt, 1u, __ATOMIC_RELAXED, __HIP_MEMORY_SCOPE_AGENT);
    }
  }
}

// =====================================================================
// FC head
// =====================================================================
__global__ void __launch_bounds__(128)
fc_kernel(const float* __restrict__ lasth, const float* __restrict__ fcW,
          const float* __restrict__ fcb, float* __restrict__ out)
{
  int tid = threadIdx.x;
  int b = tid >> 2, n = tid & 3;
  const float4* h4 = (const float4*)(lasth + (size_t)b * 512);
  const float4* w4 = (const float4*)(fcW + (size_t)n * 512);
  float s0 = 0.f, s1 = 0.f, s2 = 0.f, s3 = 0.f;
#pragma unroll 8
  for (int k = 0; k < 128; ++k) {
    float4 a = h4[k], c = w4[k];
    s0 += a.x * c.x; s1 += a.y * c.y; s2 += a.z * c.z; s3 += a.w * c.w;
  }
  out[b * 4 + n] = fcb[n] + ((s0 + s1) + (s2 + s3));
}

// =====================================================================
// Fallback: round-2 proven persistent kernel (only if ws too small)
// =====================================================================
__device__ __forceinline__ void gl2lds16(const void* gsrc, void* ldst) {
  __builtin_amdgcn_global_load_lds(
      (const __attribute__((address_space(1))) u32*)gsrc,
      (__attribute__((address_space(3))) u32*)ldst, 16, 0, 0);
}

__global__ void __launch_bounds__(256)
lstm_persist(const int* __restrict__ xidx, const int* __restrict__ attn,
             const float* __restrict__ emb,
             const float* __restrict__ Wih, const float* __restrict__ Whh,
             const float* __restrict__ bih, const float* __restrict__ bhh,
             float* __restrict__ hbuf, float* __restrict__ lasth,
             u32* __restrict__ arrive)
{
  __shared__ __align__(16) float Wl[8][1024];
  __shared__ __align__(16) float ul[2][32][64];
  __shared__ float gsc[32][8];

  const int tid  = threadIdx.x;
  const int wg   = blockIdx.x;
  const int lane = tid & 63;
  const int wv   = tid >> 6;
  const int r    = tid & 7;
  const int bb   = tid >> 3;
  const int brl  = bb & 7;

#pragma unroll 2
  for (int i = 0; i < 8; ++i) {
    int ci = i * 256 + tid;
    int rr = ci >> 8;
    int cc = ci & 255;
    int R  = ((rr >> 1) << 9) + (wg * 2 + (rr & 1));
    const float* src = (cc < 128) ? (Wih + (size_t)R * 512 + cc * 4)
                                  : (Whh + (size_t)R * 512 + (cc - 128) * 4);
    float4 v = *(const float4*)src;
    int slot = cc ^ (rr & 7);
    *(float4*)&Wl[rr][slot * 4] = v;
  }
  float bias;
  {
    int R = ((r >> 1) << 9) + (wg * 2 + (r & 1));
    bias = bih[R] + bhh[R];
  }
  {
    int pb = tid >> 3, pc = tid & 7;
    const int4* ap = (const int4*)(attn + pb * 2048 + pc * 256);
    int s = 0;
#pragma unroll 8
    for (int k = 0; k < 64; ++k) { int4 a = ap[k]; s += a.x + a.y + a.z + a.w; }
    gsc[pb][pc] = (float)s;
  }
  __syncthreads();
  int   len_reg = 0;
  float c_reg   = 0.f;
  if (tid < 64) {
    int b2 = tid & 31;
    int s = 0;
#pragma unroll
    for (int k = 0; k < 8; ++k) s += (int)gsc[b2][k];
    len_reg = s - 1;
    if (len_reg < 0) len_reg = 2047;
  }
  __syncthreads();

  const int idx_b = 8 * wv + (lane & 7);
  int idx_cur = xidx[(size_t)idx_b * 2048];

  for (int t = 0; t < T_SEQ; ++t) {
    int idx_next = (t < T_SEQ - 1) ? xidx[(size_t)idx_b * 2048 + t + 1] : 0;
    float a0 = bias, a1 = 0.f, a2 = 0.f, a3 = 0.f;
    const float* hsrc = hbuf + (((t + 1) & 1) << 14);

    auto stageE = [&](int jt, int buf) {
#pragma unroll
      for (int q = 0; q < 2; ++q) {
        int rlq = 4 * q + (lane >> 4);
        int sc = lane & 15;
        int kc = sc ^ (rlq & 7);
        int rowg = __shfl(idx_cur, rlq, 64);
        const float* g = emb + (size_t)rowg * 512 + jt * 64 + kc * 4;
        gl2lds16(g, (void*)&ul[buf][8 * wv + 4 * q][0]);
      }
    };
    auto stageH = [&](int jt, int buf) {
#pragma unroll
      for (int q = 0; q < 2; ++q) {
        int rlq = 4 * q + (lane >> 4);
        int sc = lane & 15;
        int kc = sc ^ (rlq & 7);
        int blq = 8 * wv + rlq;
        const float* g = hsrc + (size_t)blq * 512 + jt * 64 + kc * 4;
        gl2lds16(g, (void*)&ul[buf][8 * wv + 4 * q][0]);
      }
    };
    auto computeT = [&](int jg, int buf) {
#pragma unroll
      for (int kc = 0; kc < 16; ++kc) {
        float4 uv4 = *(const float4*)&ul[buf][bb][(kc ^ brl) * 4];
        float4 wv4 = *(const float4*)&Wl[r][(((jg << 4) + kc) ^ r) * 4];
        a0 += uv4.x * wv4.x; a1 += uv4.y * wv4.y;
        a2 += uv4.z * wv4.z; a3 += uv4.w * wv4.w;
      }
    };

    stageE(0, 0);
#pragma unroll
    for (int jt = 0; jt < 8; ++jt) {
      if (jt < 7) { stageE(jt + 1, (jt + 1) & 1); asm volatile("s_waitcnt vmcnt(2)" ::: "memory"); }
      else       { asm volatile("s_waitcnt vmcnt(0)" ::: "memory"); }
      computeT(jt, jt & 1);
    }

    if (tid == 0) {
      u32 target = (u32)t << 8;
      while (__hip_atomic_load(arrive, __ATOMIC_RELAXED, __HIP_MEMORY_SCOPE_AGENT) < target)
        __builtin_amdgcn_s_sleep(2);
    }
    __syncthreads();
    __builtin_amdgcn_fence(__ATOMIC_ACQUIRE, "agent");

    stageH(0, 0);
#pragma unroll
    for (int jt = 0; jt < 8; ++jt) {
      if (jt < 7) { stageH(jt + 1, (jt + 1) & 1); asm volatile("s_waitcnt vmcnt(2)" ::: "memory"); }
      else       { asm volatile("s_waitcnt vmcnt(0)" ::: "memory"); }
      computeT(8 + jt, jt & 1);
    }

    gsc[bb][r] = a0 + a1 + a2 + a3;
    __syncthreads();
    if (tid < 64) {
      int u  = tid >> 5;
      int b2 = tid & 31;
      float gi = gsc[b2][u];
      float gf = gsc[b2][2 + u];
      float gg = gsc[b2][4 + u];
      float go = gsc[b2][6 + u];
      float iv = sigm(gi), fv = sigm(gf), ov = sigm(go);
      float gv = tanhf(gg);
      c_reg = fv * c_reg + iv * gv;
      float hv = ov * tanhf(c_reg);
      int unit = (wg << 1) + u;
      hbuf[((t & 1) << 14) + (b2 << 9) + unit] = hv;
      if (t == len_reg) lasth[(b2 << 9) + unit] = hv;
      __builtin_amdgcn_fence(__ATOMIC_RELEASE, "agent");
      if (tid == 0)
        __hip_atomic_fetch_add(arrive, 1u, __ATOMIC_RELAXED, __HIP_MEMORY_SCOPE_AGENT);
    }
    idx_cur = idx_next;
  }
}

extern "C" void kernel_launch(void* const* d_in, const int* in_sizes, int n_in,
                              void* d_out, int out_size, void* d_ws, size_t ws_size,
                              hipStream_t stream) {
  const int*   x    = (const int*)d_in[0];
  const int*   attn = (const int*)d_in[1];
  const float* emb  = (const float*)d_in[2];
  const float* Wih  = (const float*)d_in[3];
  const float* Whh  = (const float*)d_in[4];
  const float* bih  = (const float*)d_in[5];
  const float* bhh  = (const float*)d_in[6];
  const float* fcW  = (const float*)d_in[7];
  const float* fcb  = (const float*)d_in[8];
  float* out = (float*)d_out;
  char* ws = (char*)d_ws;

  if (ws_size >= WS_NEED) {
    float* hbuf  = (float*)(ws + OFF_HBUF);
    u32*   cnts  = (u32*)(ws + OFF_CNT);
    float* lasth = (float*)(ws + OFF_LASTH);

    (void)hipFuncSetAttribute((const void*)lstm_seq,
                              hipFuncAttributeMaxDynamicSharedMemorySize, DYN_LDS_BYTES);
    (void)hipMemsetAsync(ws, 0, OFF_LASTH, stream);   // hbuf + counters

    hipLaunchKernelGGL(lstm_seq, dim3(NWG), dim3(512), DYN_LDS_BYTES, stream,
                       x, attn, emb, Wih, Whh, bih, bhh, hbuf, cnts, lasth);
    hipLaunchKernelGGL(fc_kernel, dim3(1), dim3(128), 0, stream,
                       lasth, fcW, fcb, out);
  } else {
    float* hbuf   = (float*)(ws + FB_OFF_HBUF);
    u32*   arrive = (u32*)(ws + FB_OFF_ARRIVE);
    float* lasth  = (float*)(ws + FB_OFF_LASTH);
    (void)hipMemsetAsync(ws, 0, 131072 + 256, stream);
    hipLaunchKernelGGL(lstm_persist, dim3(256), dim3(256), 0, stream,
                       x, attn, emb, Wih, Whh, bih, bhh, hbuf, lasth, arrive);
    hipLaunchKernelGGL(fc_kernel, dim3(1), dim3(128), 0, stream,
                       lasth, fcW, fcb, out);
  }
}